// Round 1
// baseline (73.692 us; speedup 1.0000x reference)
//
#include <hip/hip_runtime.h>
#include <math.h>

// KAN dense layer, MI355X. N_IN=N_OUT=128, K=3, G=8, BATCH=512.
// Uniform grid => closed-form cubic B-spline, only 4 nonzero basis fns per x.
#define N_IN  128
#define N_OUT 128
#define BATCH 512
#define NK    11      // G+K coeffs per edge
#define TB    16      // batch tile
#define TO    16      // output tile

__global__ __launch_bounds__(512) void kan_kernel(
    const float* __restrict__ x,       // [512][128]
    const float* __restrict__ cbasis,  // [16384][11]
    const float* __restrict__ cspl,    // [128][128]
    const float* __restrict__ cres,    // [128][128]
    const float* __restrict__ bias,    // [128]
    float* __restrict__ y)             // [512][128]
{
    // Padded LDS: per-b stride 516 words (float4 rows, +4 pad -> 2-way-max bank alias, free)
    __shared__ float sBv[TB * 516];          // 4 basis values per (b,i)
    __shared__ float sEx[TB * 258];          // (silu, base-as-int) per (b,i), stride 258
    __shared__ float sCW[TO * 258];          // (cspl, cres) per (o,i)
    __shared__ float sRed[256];

    const int b0 = blockIdx.x * TB;          // 32 blocks in x
    const int o0 = blockIdx.y * TO;          // 8 blocks in y
    const int t  = threadIdx.x;

    // ---------- Phase 1: basis + silu for TB x 128 inputs ----------
    for (int p = t; p < TB * N_IN; p += 512) {
        const int b_l = p >> 7, i = p & 127;
        const float xv = x[(b0 + b_l) * N_IN + i];
        // u in [3,11): interval index j = floor(u), local t in [0,1)
        const float u  = (xv + 1.75f) * 4.0f;
        float jf = floorf(u);
        jf = fminf(fmaxf(jf, 3.0f), 10.0f);
        const float tt  = u - jf;
        const float omt = 1.0f - tt;
        const float t2 = tt * tt, t3 = t2 * tt;
        const float B0 = omt * omt * omt * (1.0f / 6.0f);
        const float B1 = (3.0f * t3 - 6.0f * t2 + 4.0f) * (1.0f / 6.0f);
        const float B2 = (-3.0f * t3 + 3.0f * t2 + 3.0f * tt + 1.0f) * (1.0f / 6.0f);
        const float B3 = t3 * (1.0f / 6.0f);
        const int base = (int)jf - 3;        // first nonzero basis index, 0..7
        const float sig  = 1.0f / (1.0f + __expf(-xv));
        const float silu = xv * sig;
        *(float4*)&sBv[b_l * 516 + i * 4] = make_float4(B0, B1, B2, B3);
        *(float2*)&sEx[b_l * 258 + i * 2] = make_float2(silu, __int_as_float(base));
    }
    // Stage c_spl / c_res tile (coalesced)
    for (int p = t; p < TO * N_IN; p += 512) {
        const int o_l = p >> 7, i = p & 127;
        const int g = (o0 + o_l) * N_IN + i;
        *(float2*)&sCW[o_l * 258 + i * 2] = make_float2(cspl[g], cres[g]);
    }
    __syncthreads();

    // ---------- Phase 2: one thread per (b,o,i-half) ----------
    const int b_l = t & 15;
    const int o_l = (t >> 4) & 15;
    const int h   = t >> 8;                  // 0 or 1: which half of i-range
    const int o   = o0 + o_l;
    const int i0  = h * 64;

    const float2* exBase = (const float2*)&sEx[b_l * 258];
    const float4* bvBase = (const float4*)&sBv[b_l * 516];
    const float2* cwBase = (const float2*)&sCW[o_l * 258];
    const float*  cb     = cbasis + (size_t)(o * N_IN + i0) * NK;

    float acc = 0.0f;
#pragma unroll 4
    for (int ii = 0; ii < 64; ++ii) {
        const int i = i0 + ii;
        const float2 ex = exBase[i];
        const float4 bv = bvBase[i];
        const float2 cw = cwBase[i];
        const int base  = __float_as_int(ex.y);
        float4 cv;                            // 4-float gather, 4B-aligned
        __builtin_memcpy(&cv, cb + base, 16);
        const float spl = cv.x * bv.x + cv.y * bv.y + cv.z * bv.z + cv.w * bv.w;
        acc = fmaf(cw.x, spl, acc);
        acc = fmaf(cw.y, ex.x, acc);
        cb += NK;
    }

    if (h == 1) sRed[t - 256] = acc;
    __syncthreads();
    if (h == 0) {
        const float tot = acc + sRed[t] + bias[o];
        y[(b0 + b_l) * N_OUT + o] = tot;
    }
}

extern "C" void kernel_launch(void* const* d_in, const int* in_sizes, int n_in,
                              void* d_out, int out_size, void* d_ws, size_t ws_size,
                              hipStream_t stream) {
    const float* x      = (const float*)d_in[0];
    // d_in[1] = knots: unused — uniform grid is known in closed form
    const float* cbasis = (const float*)d_in[2];
    const float* cspl   = (const float*)d_in[3];
    const float* cres   = (const float*)d_in[4];
    const float* bias   = (const float*)d_in[5];
    float* y = (float*)d_out;

    dim3 grid(BATCH / TB, N_OUT / TO);   // 32 x 8 = 256 blocks
    kan_kernel<<<grid, 512, 0, stream>>>(x, cbasis, cspl, cres, bias, y);
}

// Round 2
// 71.191 us; speedup vs baseline: 1.0351x; 1.0351x over previous
//
#include <hip/hip_runtime.h>
#include <math.h>

// KAN dense layer, MI355X. N_IN=N_OUT=128, K=3, G=8, BATCH=512.
// Uniform grid => closed-form cubic B-spline, only 4 nonzero basis fns per x.
// v2: TB=8 x TO=8 tiles, 256-thread blocks, ~34 KB LDS -> 4 blocks/CU
//     (16 waves/CU vs v1's 8) to hide the LDS->gather dependent-chain latency.
#define N_IN  128
#define N_OUT 128
#define BATCH 512
#define NK    11      // G+K coeffs per edge
#define TB    8       // batch tile
#define TO    8       // output tile

__global__ __launch_bounds__(256) void kan_kernel(
    const float* __restrict__ x,       // [512][128]
    const float* __restrict__ cbasis,  // [16384][11]
    const float* __restrict__ cspl,    // [128][128]
    const float* __restrict__ cres,    // [128][128]
    const float* __restrict__ bias,    // [128]
    float* __restrict__ y)             // [512][128]
{
    // Strides 516 / 258 words: phase-2 lane mapping (8 b x 8 o per wave)
    // lands every lane-group on distinct banks (516%32=4 -> 8 b's cover all
    // 32 banks for b128; 258%32=2 -> 8 distinct even banks for b64). Conflict-free.
    __shared__ float sBv[TB * 516];          // 4 basis values per (b,i)
    __shared__ float sEx[TB * 258];          // (silu, base-as-int) per (b,i)
    __shared__ float sCW[TO * 258];          // (cspl, cres) per (o,i)
    __shared__ float sRed[256];

    const int b0 = blockIdx.x * TB;          // 64 blocks in x
    const int o0 = blockIdx.y * TO;          // 16 blocks in y
    const int t  = threadIdx.x;

    // ---------- Phase 1: basis + silu for TB x 128 inputs ----------
    for (int p = t; p < TB * N_IN; p += 256) {
        const int b_l = p >> 7, i = p & 127;
        const float xv = x[(b0 + b_l) * N_IN + i];
        const float u  = (xv + 1.75f) * 4.0f;   // u in [3,11)
        float jf = floorf(u);
        jf = fminf(fmaxf(jf, 3.0f), 10.0f);
        const float tt  = u - jf;
        const float omt = 1.0f - tt;
        const float t2 = tt * tt, t3 = t2 * tt;
        const float B0 = omt * omt * omt * (1.0f / 6.0f);
        const float B1 = (3.0f * t3 - 6.0f * t2 + 4.0f) * (1.0f / 6.0f);
        const float B2 = (-3.0f * t3 + 3.0f * t2 + 3.0f * tt + 1.0f) * (1.0f / 6.0f);
        const float B3 = t3 * (1.0f / 6.0f);
        const int base = (int)jf - 3;            // first nonzero basis idx, 0..7
        const float sig  = 1.0f / (1.0f + __expf(-xv));
        const float silu = xv * sig;
        *(float4*)&sBv[b_l * 516 + i * 4] = make_float4(B0, B1, B2, B3);
        *(float2*)&sEx[b_l * 258 + i * 2] = make_float2(silu, __int_as_float(base));
    }
    // Stage c_spl / c_res tile (coalesced)
    for (int p = t; p < TO * N_IN; p += 256) {
        const int o_l = p >> 7, i = p & 127;
        const int g = (o0 + o_l) * N_IN + i;
        *(float2*)&sCW[o_l * 258 + i * 2] = make_float2(cspl[g], cres[g]);
    }
    __syncthreads();

    // ---------- Phase 2: thread = (b_l, o_l, i-quarter) ----------
    const int b_l = t & 7;
    const int o_l = (t >> 3) & 7;
    const int h   = t >> 6;                  // 0..3: quarter of i-range
    const int o   = o0 + o_l;
    const int i0  = h * 32;

    const float2* exBase = (const float2*)&sEx[b_l * 258];
    const float4* bvBase = (const float4*)&sBv[b_l * 516];
    const float2* cwBase = (const float2*)&sCW[o_l * 258];
    const float*  cb     = cbasis + (size_t)(o * N_IN + i0) * NK;

    float acc = 0.0f;
#pragma unroll 8
    for (int ii = 0; ii < 32; ++ii) {
        const int i = i0 + ii;
        const float2 ex = exBase[i];
        const float4 bv = bvBase[i];
        const float2 cw = cwBase[i];
        const int base  = __float_as_int(ex.y);
        float4 cv;                            // 4-float gather, 4B-aligned
        __builtin_memcpy(&cv, cb + base, 16);
        const float spl = cv.x * bv.x + cv.y * bv.y + cv.z * bv.z + cv.w * bv.w;
        acc = fmaf(cw.x, spl, acc);
        acc = fmaf(cw.y, ex.x, acc);
        cb += NK;
    }

    sRed[t] = acc;
    __syncthreads();
    if (h == 0) {
        const float tot = sRed[t] + sRed[t + 64] + sRed[t + 128] + sRed[t + 192]
                        + bias[o];
        y[(b0 + b_l) * N_OUT + o] = tot;
    }
}

extern "C" void kernel_launch(void* const* d_in, const int* in_sizes, int n_in,
                              void* d_out, int out_size, void* d_ws, size_t ws_size,
                              hipStream_t stream) {
    const float* x      = (const float*)d_in[0];
    // d_in[1] = knots: unused — uniform grid is known in closed form
    const float* cbasis = (const float*)d_in[2];
    const float* cspl   = (const float*)d_in[3];
    const float* cres   = (const float*)d_in[4];
    const float* bias   = (const float*)d_in[5];
    float* y = (float*)d_out;

    dim3 grid(BATCH / TB, N_OUT / TO);   // 64 x 16 = 1024 blocks
    kan_kernel<<<grid, 256, 0, stream>>>(x, cbasis, cspl, cres, bias, y);
}